// Round 13
// baseline (411.810 us; speedup 1.0000x reference)
//
#include <hip/hip_runtime.h>
#include <math.h>

#define HD 128      // hidden dim (= F_IN)
#define ED 16       // edge feat dim
#define NG 64       // num graphs
#define NC 10       // num classes
#define EPB_LOG 14  // edges per hist slice = 16384 (= nodes per range)
#define EPB (1<<EPB_LOG)

typedef short bf16x8 __attribute__((ext_vector_type(8)));
typedef float f32x4 __attribute__((ext_vector_type(4)));

__device__ __forceinline__ unsigned short f2b(float x){
  unsigned u = __float_as_uint(x);
  unsigned r = (u + 0x7fffu + ((u >> 16) & 1u)) >> 16;
  return (unsigned short)r;
}
__device__ __forceinline__ float blo(unsigned p){ return __uint_as_float(p << 16); }
__device__ __forceinline__ float bhi(unsigned p){ return __uint_as_float(p & 0xffff0000u); }
__device__ __forceinline__ float bperm_f(int idx, float v){
  return __int_as_float(__builtin_amdgcn_ds_bpermute(idx<<2, __float_as_int(v)));
}
__device__ __forceinline__ int bperm_i(int idx, int v){
  return __builtin_amdgcn_ds_bpermute(idx<<2, v);
}
// load 8 consecutive f32 and round-to-nearest-even to a bf16x8 fragment
__device__ __forceinline__ bf16x8 ld8f32_bf16(const float* p){
  float4 u0 = *(const float4*)p;
  float4 u1 = *(const float4*)(p+4);
  uint4 o;
  o.x = f2b(u0.x) | ((unsigned)f2b(u0.y)<<16);
  o.y = f2b(u0.z) | ((unsigned)f2b(u0.w)<<16);
  o.z = f2b(u1.x) | ((unsigned)f2b(u1.y)<<16);
  o.w = f2b(u1.z) | ((unsigned)f2b(u1.w)<<16);
  return __builtin_bit_cast(bf16x8, o);
}

// ================= LDS-hist: one block per (slice, node-range), zero global atomics =================
__global__ __launch_bounds__(256) void k_hist(const int* __restrict__ dst,
                                              unsigned short* __restrict__ H16, int Nr2,
                                              int* __restrict__ rank, int NP, int E, int N){
  __shared__ unsigned hls[EPB/2];     // 32 KB
  int kb = blockIdx.x / NP, ps = blockIdx.x - kb*NP;
  int e0 = kb << EPB_LOG;
  int e1 = e0 + EPB; if(e1 > E) e1 = E;
  int h0 = ps << EPB_LOG;
  for(int w=threadIdx.x; w<EPB/2; w+=256) hls[w] = 0u;
  __syncthreads();
  for(int e=e0+threadIdx.x; e<e1; e+=256){
    int d = dst[e];
    unsigned rel = (unsigned)(d - h0);
    if(rel < (unsigned)EPB){
      unsigned add = (rel & 1u) ? 0x10000u : 1u;
      unsigned old = atomicAdd(&hls[rel>>1], add);
      rank[e] = (int)((old >> ((rel & 1u)*16u)) & 0xffffu);
    }
  }
  __syncthreads();
  int nodes = N - h0; if(nodes > EPB) nodes = EPB;
  if(nodes > 0){
    int words = (nodes + 1) >> 1;
    unsigned* Hg = (unsigned*)(H16 + (size_t)kb*Nr2 + h0);
    for(int w=threadIdx.x; w<words; w+=256) Hg[w] = hls[w];
  }
}

// ================= merged pre-kernel (NO LDS -> full stream occupancy) =================
// edge-dots -> pay[e] | W swizzle | cnt | hg zero
__global__ __launch_bounds__(256) void k_pre(
    int NE4, int E,
    const int* __restrict__ src, const float* __restrict__ ef,
    const float* __restrict__ a1e, const float* __restrict__ a2e,
    const float* __restrict__ a3e, uint2* __restrict__ pay,
    const float* __restrict__ W1, const float* __restrict__ W2, const float* __restrict__ W3,
    unsigned short* __restrict__ Wb,
    const int* __restrict__ gid, float* __restrict__ cnt,
    float* __restrict__ hg,
    int N){
  int b = blockIdx.x;
  if(b < NE4){
    // ---- edge dots: 4 lanes/edge, write full 8B record payload at pos e ----
    int t = b*256 + threadIdx.x;
    int e = t >> 2;
    int sub = t & 3;
    if(e >= E) return;
    float4 f  = *(const float4*)&ef[(size_t)e*ED + sub*4];
    float4 A1 = *(const float4*)&a1e[sub*4];
    float4 A2 = *(const float4*)&a2e[sub*4];
    float4 A3 = *(const float4*)&a3e[sub*4];
    float q1 = fmaf(f.x,A1.x, fmaf(f.y,A1.y, fmaf(f.z,A1.z, f.w*A1.w)));
    float q2 = fmaf(f.x,A2.x, fmaf(f.y,A2.y, fmaf(f.z,A2.z, f.w*A2.w)));
    float q3 = fmaf(f.x,A3.x, fmaf(f.y,A3.y, fmaf(f.z,A3.z, f.w*A3.w)));
    q1 += __shfl_xor(q1,1); q1 += __shfl_xor(q1,2);
    q2 += __shfl_xor(q2,1); q2 += __shfl_xor(q2,2);
    q3 += __shfl_xor(q3,1); q3 += __shfl_xor(q3,2);
    if(sub == 0){
      uint2 A;
      A.x = (unsigned)f2b(q1) | ((unsigned)f2b(q2) << 16);
      A.y = (unsigned)src[e] | ((unsigned)f2b(q3) << 16);
      pay[e] = A;
    }
    return;
  }
  b -= NE4;
  if(b < 24){
    // ---- W swizzle (3 layers x 2048 rows) ----
    int idx = b*256 + threadIdx.x;
    if(idx >= 3*2048) return;
    int layer = idx >> 11;
    int r = idx & 2047;
    const float* W = (layer==0)?W1:((layer==1)?W2:W3);
    int lane = r & 63, tile = r >> 6;
    int kt = tile >> 3, nt = tile & 7;
    int qq = lane >> 4, cc = lane & 15;
    int kbase = kt*32 + qq*8;
    int col = nt*16 + cc;
    unsigned short tmp[8];
    #pragma unroll
    for(int j=0;j<8;j++) tmp[j] = f2b(W[(size_t)(kbase+j)*HD + col]);
    uint4 o;
    o.x = tmp[0]|((unsigned)tmp[1]<<16); o.y = tmp[2]|((unsigned)tmp[3]<<16);
    o.z = tmp[4]|((unsigned)tmp[5]<<16); o.w = tmp[6]|((unsigned)tmp[7]<<16);
    *(uint4*)&Wb[(size_t)idx*8] = o;
    return;
  }
  b -= 24;
  if(b == 0){
    // ---- per-graph node counts ----
    int g = threadIdx.x;
    if(g >= NG) return;
    int lo=0, hi=N;
    while(lo<hi){ int mid=(lo+hi)>>1; if(gid[mid] < g) lo=mid+1; else hi=mid; }
    int start = lo; lo = start; hi = N;
    while(lo<hi){ int mid=(lo+hi)>>1; if(gid[mid] < g+1) lo=mid+1; else hi=mid; }
    cnt[g] = (float)(lo - start);
    return;
  }
  b -= 1;
  // ---- hg zero: 3*NG*HD floats, 24 blocks ----
  int i = (b*256 + threadIdx.x)*4;
  if(i < 3*NG*HD) *(float4*)&hg[i] = (float4){0.f,0.f,0.f,0.f};
}

// deg[i] = sum over slices; block sum -> bsum[b]  (depends on H16 complete)
__global__ __launch_bounds__(256) void k_degsum(const unsigned short* __restrict__ H16,
                                                int Nr2, int NB,
                                                int* __restrict__ deg,
                                                int* __restrict__ bsum, int N){
  __shared__ int rs[4];
  int b = blockIdx.x;
  int i = b*256 + threadIdx.x;
  int s = 0;
  if(i < N){
    for(int k=0;k<NB;k++) s += (int)H16[(size_t)k*Nr2 + i];
    deg[i] = s;
  }
  #pragma unroll
  for(int o=32;o;o>>=1) s += __shfl_xor(s,o);
  if((threadIdx.x&63)==0) rs[threadIdx.x>>6] = s;
  __syncthreads();
  if(threadIdx.x==0) bsum[b] = rs[0]+rs[1]+rs[2]+rs[3];
}

// bprop with inline prefix of bsum; emits offs and SLICE-MAJOR offs2[k][i]
__global__ __launch_bounds__(256) void k_bprop2(const int* __restrict__ deg,
                                                const int* __restrict__ bsum,
                                                const unsigned short* __restrict__ H16, int Nr2,
                                                int* __restrict__ offs,
                                                int* __restrict__ offs2, int Nr,
                                                int N, int E, int NB){
  __shared__ int sh[256];
  __shared__ int sbase;
  int b = blockIdx.x, t = threadIdx.x;
  int s = 0;
  for(int j=t; j<b; j+=256) s += bsum[j];
  #pragma unroll
  for(int o=32;o;o>>=1) s += __shfl_xor(s,o);
  if(t < 4) sh[t] = 0;
  __syncthreads();
  if((t&63)==0) sh[t>>6] = s;
  __syncthreads();
  if(t==0) sbase = sh[0]+sh[1]+sh[2]+sh[3];
  __syncthreads();
  int i = b*256 + t;
  int v = (i<N) ? deg[i] : 0;
  sh[t] = v; __syncthreads();
  for(int o=1;o<256;o<<=1){ int u = (t>=o)?sh[t-o]:0; __syncthreads(); sh[t]+=u; __syncthreads(); }
  if(i<N){
    int base = sbase + sh[t] - v;
    offs[i] = base;
    int run = base;
    for(int k=0;k<NB;k++){
      offs2[(size_t)k*Nr + i] = run;
      run += (int)H16[(size_t)k*Nr2 + i];
    }
  }
  if(b==0 && t==0) offs[N] = E;
}

// ================= device bodies reused by merged kernels =================

// THIN scatter: slice id = e>>EPB_LOG (wave-uniform), rank is LDS-local rank.
__device__ __forceinline__ void scatter_dev(int bidx,
                           const int* __restrict__ dst, const int* __restrict__ rank,
                           const uint2* __restrict__ pay,
                           const int* __restrict__ offs2, int Nr,
                           uint2* __restrict__ rec, int E){
  int e = bidx*256 + threadIdx.x;
  if(e >= E) return;
  int d = dst[e];
  int k = e >> EPB_LOG;
  int p = offs2[(size_t)k*Nr + d] + rank[e];
  rec[p] = pay[e];
}

// MFMA GEMM tile + fused pdots. A-operand: bf16 (Ab) or f32 (Af, converted
// in-register with identical rounding).
__device__ __forceinline__ void gemm_dev(int bidx,
    const unsigned short* __restrict__ Ab,
    const float* __restrict__ Af,
    const unsigned short* __restrict__ Wb,
    unsigned short* __restrict__ Zb,
    const float* __restrict__ avec,
    float* __restrict__ ps, float* __restrict__ pd, int M)
{
  int tid = threadIdx.x;
  int w = tid >> 6, lane = tid & 63;
  int q = lane >> 4, c = lane & 15;
  int rowbase = bidx*128 + w*32;
  f32x4 acc[2][8];
  #pragma unroll
  for(int t=0;t<2;t++)
    #pragma unroll
    for(int n=0;n<8;n++) acc[t][n] = (f32x4){0.f,0.f,0.f,0.f};

  int r0 = rowbase + c;      if(r0 > M-1) r0 = M-1;
  int r1 = rowbase + 16 + c; if(r1 > M-1) r1 = M-1;
  #pragma unroll
  for(int kt=0; kt<4; kt++){
    int ko = kt*32 + q*8;
    bf16x8 a0, a1;
    if(Af){
      a0 = ld8f32_bf16(&Af[(size_t)r0*HD + ko]);
      a1 = ld8f32_bf16(&Af[(size_t)r1*HD + ko]);
    } else {
      a0 = __builtin_bit_cast(bf16x8, *(const uint4*)&Ab[(size_t)r0*HD + ko]);
      a1 = __builtin_bit_cast(bf16x8, *(const uint4*)&Ab[(size_t)r1*HD + ko]);
    }
    #pragma unroll
    for(int n=0;n<8;n++){
      bf16x8 b = __builtin_bit_cast(bf16x8, *(const uint4*)&Wb[(((size_t)(kt*8+n))*64 + lane)*8]);
      acc[0][n] = __builtin_amdgcn_mfma_f32_16x16x32_bf16(a0, b, acc[0][n], 0,0,0);
      acc[1][n] = __builtin_amdgcn_mfma_f32_16x16x32_bf16(a1, b, acc[1][n], 0,0,0);
    }
  }
  float asv[8], adv[8];
  #pragma unroll
  for(int n=0;n<8;n++){ asv[n] = avec[n*16+c]; adv[n] = avec[HD + n*16+c]; }
  #pragma unroll
  for(int t=0;t<2;t++){
    #pragma unroll
    for(int r=0;r<4;r++){
      int grow = rowbase + t*16 + 4*q + r;
      bool ok = grow < M;
      #pragma unroll
      for(int n=0;n<8;n++){
        if(ok) Zb[(size_t)grow*HD + n*16 + c] = f2b(acc[t][n][r]);
      }
      float pp = 0.f, dd = 0.f;
      #pragma unroll
      for(int n=0;n<8;n++){ pp = fmaf(acc[t][n][r], asv[n], pp); dd = fmaf(acc[t][n][r], adv[n], dd); }
      #pragma unroll
      for(int o=1;o<16;o<<=1){ pp += __shfl_xor(pp,o); dd += __shfl_xor(dd,o); }
      if(ok && c==0){ ps[grow] = pp; pd[grow] = dd; }
    }
  }
}

// readout chunk, 256-thread shape: 4 chunks (one per 64-lane group) of one graph
#define RCH 16
__device__ __forceinline__ void readout_dev(int rb,
                          const unsigned* __restrict__ hbu,
                          const float* __restrict__ att,
                          const int* __restrict__ gid,
                          float* __restrict__ hg, int N){
  int g = rb >> 2;
  int chunk = ((rb & 3) << 2) + (threadIdx.x >> 6);
  int t = threadIdx.x & 63;
  int lo=0, hi=N;
  while(lo<hi){ int mid=(lo+hi)>>1; if(gid[mid] < g) lo=mid+1; else hi=mid; }
  int start = lo; lo = start; hi = N;
  while(lo<hi){ int mid=(lo+hi)>>1; if(gid[mid] < g+1) lo=mid+1; else hi=mid; }
  int end = lo;
  int len = end - start;
  int c0 = start + (int)(((long long)len * chunk) / RCH);
  int c1 = start + (int)(((long long)len * (chunk+1)) / RCH);
  float acc0 = 0.f, acc1 = 0.f;
  for(int v=c0; v<c1; v++){
    unsigned P = hbu[(size_t)v*64 + t];
    float a = att[v];
    acc0 = fmaf(a, blo(P), acc0);
    acc1 = fmaf(a, bhi(P), acc1);
  }
  atomicAdd(&hg[g*HD + 2*t],     acc0);
  atomicAdd(&hg[g*HD + 2*t + 1], acc1);
}

// ================= merged dispatches =================
// thin-scatter ∥ gemm(layer1, f32 A-path)
__global__ __launch_bounds__(256) void k_sg1(
    const float* __restrict__ x, const unsigned short* __restrict__ Wb,
    unsigned short* __restrict__ Zb, const float* __restrict__ avec,
    float* __restrict__ ps, float* __restrict__ pd, int M, int GB,
    const int* __restrict__ dst, const int* __restrict__ rank,
    const uint2* __restrict__ pay,
    const int* __restrict__ offs2, int Nr, uint2* __restrict__ rec, int E){
  if(blockIdx.x < GB) gemm_dev(blockIdx.x, (const unsigned short*)0, x, Wb, Zb, avec, ps, pd, M);
  else scatter_dev(blockIdx.x - GB, dst, rank, pay, offs2, Nr, rec, E);
}

// readout(L) ∥ gemm(L+1)
__global__ __launch_bounds__(256) void k_rg(
    const unsigned short* __restrict__ Ab, const unsigned short* __restrict__ Wb,
    unsigned short* __restrict__ Zb, const float* __restrict__ avec,
    float* __restrict__ ps, float* __restrict__ pd, int M, int GB,
    const unsigned* __restrict__ hbu, const float* __restrict__ att,
    const int* __restrict__ gid, float* __restrict__ hg, int N){
  if(blockIdx.x < GB) gemm_dev(blockIdx.x, Ab, (const float*)0, Wb, Zb, avec, ps, pd, M);
  else readout_dev(blockIdx.x - GB, hbu, att, gid, hg, N);
}

// ---------------- fused logits + softmax + aggregate + relu + h(bf16) + att ----------------
// PROVEN 43us inner structure (R2), now GRID-STRIDE: 2048 long-lived blocks
// (one per CU slot) instead of 12500 ~0.3us blocks -> no CP dispatch churn.
__global__ __launch_bounds__(256) void k_agg2(const uint4* __restrict__ zb4,
                                              const int* __restrict__ offs,
                                              const uint2* __restrict__ rec,
                                              const float* __restrict__ ps,
                                              const float* __restrict__ pd,
                                              int layer,
                                              unsigned* __restrict__ hbu,
                                              float* __restrict__ att,
                                              const float* __restrict__ watt,
                                              const float* __restrict__ batt, int N){
  int lane = threadIdx.x & 63;
  int q = lane >> 4, c = lane & 15;
  float4 w0v = *(const float4*)&watt[c*8];
  float4 w1v = *(const float4*)&watt[c*8+4];
  float bat = batt[0];
  int stride = gridDim.x << 2;

  for(int wid = blockIdx.x*4 + (threadIdx.x>>6); wid < N; wid += stride){
    int d0 = offs[wid], d1 = offs[wid+1];
    float pdv = pd[wid];
    float acc[8];
    #pragma unroll
    for(int i=0;i<8;i++) acc[i]=0.f;
    float ssum = 0.f;

    for(int t0=d0; t0<d1; t0+=64){
      int rem = d1 - t0; if(rem > 64) rem = 64;
      // ---- phase 1: per-lane edge weight ----
      int j = t0 + lane;
      float w = 0.f; int u = 0;
      if(j < d1){
        uint2 R = rec[j];
        u = (int)(R.y & 0xffffu);
        unsigned qb = (layer==0) ? (R.x & 0xffffu) : (layer==1 ? (R.x >> 16) : (R.y >> 16));
        float ql = __uint_as_float(qb << 16);
        float l = ps[u] + pdv + ql;
        l = (l >= 0.f) ? l : 0.2f*l;
        w = __expf(l);
      }
      float ws = w;
      #pragma unroll
      for(int o=32;o;o>>=1) ws += __shfl_xor(ws,o);
      ssum += ws;
      // ---- phase 2: 16 edges per iteration ----
      for(int jb=0; jb<rem; jb+=16){
        float w0 = bperm_f(jb+q,    w);  int u0 = bperm_i(jb+q,    u);
        float w1 = bperm_f(jb+4+q,  w);  int u1 = bperm_i(jb+4+q,  u);
        float w2 = bperm_f(jb+8+q,  w);  int u2 = bperm_i(jb+8+q,  u);
        float w3 = bperm_f(jb+12+q, w);  int u3 = bperm_i(jb+12+q, u);
        uint4 P0 = zb4[(size_t)u0*16 + c];
        uint4 P1 = zb4[(size_t)u1*16 + c];
        uint4 P2 = zb4[(size_t)u2*16 + c];
        uint4 P3 = zb4[(size_t)u3*16 + c];
        acc[0] = fmaf(w0, blo(P0.x), acc[0]); acc[1] = fmaf(w0, bhi(P0.x), acc[1]);
        acc[2] = fmaf(w0, blo(P0.y), acc[2]); acc[3] = fmaf(w0, bhi(P0.y), acc[3]);
        acc[4] = fmaf(w0, blo(P0.z), acc[4]); acc[5] = fmaf(w0, bhi(P0.z), acc[5]);
        acc[6] = fmaf(w0, blo(P0.w), acc[6]); acc[7] = fmaf(w0, bhi(P0.w), acc[7]);
        acc[0] = fmaf(w1, blo(P1.x), acc[0]); acc[1] = fmaf(w1, bhi(P1.x), acc[1]);
        acc[2] = fmaf(w1, blo(P1.y), acc[2]); acc[3] = fmaf(w1, bhi(P1.y), acc[3]);
        acc[4] = fmaf(w1, blo(P1.z), acc[4]); acc[5] = fmaf(w1, bhi(P1.z), acc[5]);
        acc[6] = fmaf(w1, blo(P1.w), acc[6]); acc[7] = fmaf(w1, bhi(P1.w), acc[7]);
        acc[0] = fmaf(w2, blo(P2.x), acc[0]); acc[1] = fmaf(w2, bhi(P2.x), acc[1]);
        acc[2] = fmaf(w2, blo(P2.y), acc[2]); acc[3] = fmaf(w2, bhi(P2.y), acc[3]);
        acc[4] = fmaf(w2, blo(P2.z), acc[4]); acc[5] = fmaf(w2, bhi(P2.z), acc[5]);
        acc[6] = fmaf(w2, blo(P2.w), acc[6]); acc[7] = fmaf(w2, bhi(P2.w), acc[7]);
        acc[0] = fmaf(w3, blo(P3.x), acc[0]); acc[1] = fmaf(w3, bhi(P3.x), acc[1]);
        acc[2] = fmaf(w3, blo(P3.y), acc[2]); acc[3] = fmaf(w3, bhi(P3.y), acc[3]);
        acc[4] = fmaf(w3, blo(P3.z), acc[4]); acc[5] = fmaf(w3, bhi(P3.z), acc[5]);
        acc[6] = fmaf(w3, blo(P3.w), acc[6]); acc[7] = fmaf(w3, bhi(P3.w), acc[7]);
      }
    }
    #pragma unroll
    for(int i=0;i<8;i++){ acc[i] += __shfl_xor(acc[i],16); acc[i] += __shfl_xor(acc[i],32); }
    float inv = (d1 > d0) ? 1.0f/ssum : 0.0f;
    #pragma unroll
    for(int i=0;i<8;i++) acc[i] = fmaxf(acc[i]*inv, 0.f);
    hbu[(size_t)wid*64 + c*4 + q] = (unsigned)f2b(acc[2*q]) | ((unsigned)f2b(acc[2*q+1])<<16);
    float t = acc[0]*w0v.x + acc[1]*w0v.y + acc[2]*w0v.z + acc[3]*w0v.w
            + acc[4]*w1v.x + acc[5]*w1v.y + acc[6]*w1v.z + acc[7]*w1v.w;
    #pragma unroll
    for(int o=1;o<16;o<<=1) t += __shfl_xor(t,o);
    t += bat;
    float lr = (t >= 0.f) ? t : 0.01f*t;
    if(lane==0) att[wid] = __expf(lr);
  }
}

// ---------------- standalone readout for layer 3 ----------------
__global__ __launch_bounds__(64) void k_readout(const unsigned* __restrict__ hbu,
                                                const float* __restrict__ att,
                                                const int* __restrict__ gid,
                                                float* __restrict__ hg, int N){
  int g = blockIdx.x / RCH;
  int chunk = blockIdx.x % RCH;
  int t = threadIdx.x;
  int lo=0, hi=N;
  while(lo<hi){ int mid=(lo+hi)>>1; if(gid[mid] < g) lo=mid+1; else hi=mid; }
  int start = lo; lo = start; hi = N;
  while(lo<hi){ int mid=(lo+hi)>>1; if(gid[mid] < g+1) lo=mid+1; else hi=mid; }
  int end = lo;
  int len = end - start;
  int c0 = start + (int)(((long long)len * chunk) / RCH);
  int c1 = start + (int)(((long long)len * (chunk+1)) / RCH);
  float acc0 = 0.f, acc1 = 0.f;
  for(int v=c0; v<c1; v++){
    unsigned P = hbu[(size_t)v*64 + t];
    float a = att[v];
    acc0 = fmaf(a, blo(P), acc0);
    acc1 = fmaf(a, bhi(P), acc1);
  }
  atomicAdd(&hg[g*HD + 2*t],     acc0);
  atomicAdd(&hg[g*HD + 2*t + 1], acc1);
}

// ---------------- final classifier + log_softmax (block per graph) ----------------
__global__ __launch_bounds__(384) void k_final(const float* __restrict__ hg,
                                               const float* __restrict__ cnt,
                                               const float* __restrict__ Wc,
                                               const float* __restrict__ bc,
                                               float* __restrict__ out){
  int g = blockIdx.x;
  int t = threadIdx.x;
  __shared__ float red[6];
  __shared__ float yv[NC];
  float invc = 1.f / fmaxf(cnt[g], 1.f);
  int part = t >> 7;
  int f = t & 127;
  float v = hg[(size_t)part*NG*HD + g*HD + f] * invc;
  for(int c=0; c<NC; c++){
    float p = v * Wc[(size_t)t*NC + c];
    #pragma unroll
    for(int o=32;o;o>>=1) p += __shfl_xor(p,o);
    if((t&63)==0) red[t>>6] = p;
    __syncthreads();
    if(t==0) yv[c] = bc[c] + red[0]+red[1]+red[2]+red[3]+red[4]+red[5];
    __syncthreads();
  }
  if(t==0){
    float mx = -INFINITY;
    #pragma unroll
    for(int c=0;c<NC;c++) mx = fmaxf(mx, yv[c]);
    float s = 0.f;
    #pragma unroll
    for(int c=0;c<NC;c++) s += __expf(yv[c] - mx);
    float ls = logf(s);
    #pragma unroll
    for(int c=0;c<NC;c++) out[g*NC + c] = yv[c] - mx - ls;
  }
}

// ---------------- host ----------------
extern "C" void kernel_launch(void* const* d_in, const int* in_sizes, int n_in,
                              void* d_out, int out_size, void* d_ws, size_t ws_size,
                              hipStream_t stream) {
  const float* x     = (const float*)d_in[0];
  const float* efeat = (const float*)d_in[1];
  const int*   src   = (const int*)d_in[2];
  const int*   dst   = (const int*)d_in[3];
  const int*   gid   = (const int*)d_in[4];
  const float* W1    = (const float*)d_in[5];
  const float* a1    = (const float*)d_in[6];
  const float* W2    = (const float*)d_in[7];
  const float* a2    = (const float*)d_in[8];
  const float* W3    = (const float*)d_in[9];
  const float* a3    = (const float*)d_in[10];
  const float* watt  = (const float*)d_in[11];
  const float* batt  = (const float*)d_in[12];
  const float* Wc    = (const float*)d_in[13];
  const float* bc    = (const float*)d_in[14];
  float* out = (float*)d_out;

  int N = in_sizes[4];
  int E = in_sizes[2];
  int Nr = (N + 63) & ~63;                    // offs2 node stride
  int NB = (E + EPB - 1) >> EPB_LOG;          // hist slices
  int NP = (N + EPB - 1) >> EPB_LOG;          // node-range passes
  int NBH = NB * NP;                          // hist blocks
  int Nr2 = NP << EPB_LOG;                    // H16 node stride

  char* p = (char*)d_ws;
  auto alloc = [&](size_t bytes)->void*{
    void* r = (void*)p;
    p += (bytes + 255) & ~(size_t)255;
    return r;
  };
  unsigned short* Hb = (unsigned short*)alloc((size_t)N*HD*2);
  unsigned short* Zb = (unsigned short*)alloc((size_t)N*HD*2);
  unsigned short* Wball = (unsigned short*)alloc((size_t)3*2048*8*2);
  float* ps      = (float*)alloc((size_t)N*4);
  float* pd      = (float*)alloc((size_t)N*4);
  float* att     = (float*)alloc((size_t)N*4);
  int*   deg     = (int*)  alloc((size_t)N*4);
  int*   offs    = (int*)  alloc((size_t)(N+1)*4);
  int*   offs2   = (int*)  alloc((size_t)NB*Nr*4);
  unsigned short* H16 = (unsigned short*)alloc((size_t)NB*Nr2*2);
  int*   rank    = (int*)  alloc((size_t)E*4);
  uint2* pay     = (uint2*)alloc((size_t)E*8);
  uint2* rec     = (uint2*)alloc((size_t)E*8);
  int*   bsum    = (int*)  alloc((size_t)1024*4);
  float* hg      = (float*)alloc((size_t)3*NG*HD*4);
  float* cnt     = (float*)alloc((size_t)NG*4);
  (void)ws_size; (void)n_in; (void)out_size;

  int nb = (N + 255) / 256;
  int NE4 = (E*4 + 255) / 256;
  int GB = (N + 127) / 128;
  int SB = (E + 255) / 256;
  int nagg = (N + 3) / 4; if(nagg > 2048) nagg = 2048;

  // CSR build with LDS histograms (196-way parallel)
  k_hist<<<NBH, 256, 0, stream>>>(dst, H16, Nr2, rank, NP, E, N);
  k_pre<<<NE4 + 24 + 1 + 24, 256, 0, stream>>>(NE4, E,
                                               src, efeat, a1+2*HD, a2+2*HD, a3+2*HD, pay,
                                               W1, W2, W3, Wball,
                                               gid, cnt, hg, N);
  k_degsum<<<nb, 256, 0, stream>>>(H16, Nr2, NB, deg, bsum, N);
  k_bprop2<<<nb, 256, 0, stream>>>(deg, bsum, H16, Nr2, offs, offs2, Nr, N, E, NB);
  // thin scatter ∥ gemm layer 1 (f32 A-path)
  k_sg1<<<GB + SB, 256, 0, stream>>>(x, Wball, Zb, a1, ps, pd, N, GB,
                                     dst, rank, pay, offs2, Nr, rec, E);
  k_agg2<<<nagg, 256, 0, stream>>>((const uint4*)Zb, offs, rec, ps, pd, 0,
                                   (unsigned*)Hb, att, watt, batt, N);
  // readout L1 ∥ gemm L2
  k_rg<<<GB + NG*4, 256, 0, stream>>>(Hb, Wball + (size_t)1*2048*8, Zb, a2, ps, pd, N, GB,
                                      (const unsigned*)Hb, att, gid, hg + 0*NG*HD, N);
  k_agg2<<<nagg, 256, 0, stream>>>((const uint4*)Zb, offs, rec, ps, pd, 1,
                                   (unsigned*)Hb, att, watt, batt, N);
  // readout L2 ∥ gemm L3
  k_rg<<<GB + NG*4, 256, 0, stream>>>(Hb, Wball + (size_t)2*2048*8, Zb, a3, ps, pd, N, GB,
                                      (const unsigned*)Hb, att, gid, hg + 1*NG*HD, N);
  k_agg2<<<nagg, 256, 0, stream>>>((const uint4*)Zb, offs, rec, ps, pd, 2,
                                   (unsigned*)Hb, att, watt, batt, N);
  k_readout<<<NG*RCH, 64, 0, stream>>>((const unsigned*)Hb, att, gid,
                                       hg + 2*NG*HD, N);
  k_final<<<NG, 384, 0, stream>>>(hg, cnt, Wc, bc, out);
}

// Round 14
// 396.457 us; speedup vs baseline: 1.0387x; 1.0387x over previous
//
#include <hip/hip_runtime.h>
#include <math.h>

#define HD 128      // hidden dim (= F_IN)
#define ED 16       // edge feat dim
#define NG 64       // num graphs
#define NC 10       // num classes
#define EPB_LOG 14  // edges per hist slice = 16384 (= nodes per range)
#define EPB (1<<EPB_LOG)

typedef short bf16x8 __attribute__((ext_vector_type(8)));
typedef float f32x4 __attribute__((ext_vector_type(4)));

__device__ __forceinline__ unsigned short f2b(float x){
  unsigned u = __float_as_uint(x);
  unsigned r = (u + 0x7fffu + ((u >> 16) & 1u)) >> 16;
  return (unsigned short)r;
}
__device__ __forceinline__ float blo(unsigned p){ return __uint_as_float(p << 16); }
__device__ __forceinline__ float bhi(unsigned p){ return __uint_as_float(p & 0xffff0000u); }
__device__ __forceinline__ float bperm_f(int idx, float v){
  return __int_as_float(__builtin_amdgcn_ds_bpermute(idx<<2, __float_as_int(v)));
}
__device__ __forceinline__ int bperm_i(int idx, int v){
  return __builtin_amdgcn_ds_bpermute(idx<<2, v);
}
// load 8 consecutive f32 and round-to-nearest-even to a bf16x8 fragment
__device__ __forceinline__ bf16x8 ld8f32_bf16(const float* p){
  float4 u0 = *(const float4*)p;
  float4 u1 = *(const float4*)(p+4);
  uint4 o;
  o.x = f2b(u0.x) | ((unsigned)f2b(u0.y)<<16);
  o.y = f2b(u0.z) | ((unsigned)f2b(u0.w)<<16);
  o.z = f2b(u1.x) | ((unsigned)f2b(u1.y)<<16);
  o.w = f2b(u1.z) | ((unsigned)f2b(u1.w)<<16);
  return __builtin_bit_cast(bf16x8, o);
}

// ================= merged pre-kernel (R12 structure: hist inside) =================
// LDS-hist (one block per slice x node-range) | edge-dots | W swizzle | cnt |
// hg zero. Hist blocks schedule first; stream blocks fill remaining CUs and
// hide them. ZERO global atomics.
__global__ __launch_bounds__(256) void k_pre(
    const int* __restrict__ dst, unsigned short* __restrict__ H16, int Nr2,
    int* __restrict__ rank, int NBH, int NP,
    int NE4, int E,
    const int* __restrict__ src, const float* __restrict__ ef,
    const float* __restrict__ a1e, const float* __restrict__ a2e,
    const float* __restrict__ a3e, uint2* __restrict__ pay,
    const float* __restrict__ W1, const float* __restrict__ W2, const float* __restrict__ W3,
    unsigned short* __restrict__ Wb,
    const int* __restrict__ gid, float* __restrict__ cnt,
    float* __restrict__ hg,
    int N){
  __shared__ unsigned hls[EPB/2];     // 32 KB (hist blocks only)
  int b = blockIdx.x;
  if(b < NBH){
    // ---- hist: slice kb, node-range ps. LDS atomicAdd return = local rank ----
    int kb = b / NP, ps = b - kb*NP;
    int e0 = kb << EPB_LOG;
    int e1 = e0 + EPB; if(e1 > E) e1 = E;
    int h0 = ps << EPB_LOG;
    for(int w=threadIdx.x; w<EPB/2; w+=256) hls[w] = 0u;
    __syncthreads();
    for(int e=e0+threadIdx.x; e<e1; e+=256){
      int d = dst[e];
      unsigned rel = (unsigned)(d - h0);
      if(rel < (unsigned)EPB){
        unsigned add = (rel & 1u) ? 0x10000u : 1u;
        unsigned old = atomicAdd(&hls[rel>>1], add);
        rank[e] = (int)((old >> ((rel & 1u)*16u)) & 0xffffu);
      }
    }
    __syncthreads();
    int nodes = N - h0; if(nodes > EPB) nodes = EPB;
    if(nodes > 0){
      int words = (nodes + 1) >> 1;
      unsigned* Hg = (unsigned*)(H16 + (size_t)kb*Nr2 + h0);
      for(int w=threadIdx.x; w<words; w+=256) Hg[w] = hls[w];
    }
    return;
  }
  b -= NBH;
  if(b < NE4){
    // ---- edge dots: 4 lanes/edge, write full 8B record payload at pos e ----
    int t = b*256 + threadIdx.x;
    int e = t >> 2;
    int sub = t & 3;
    if(e >= E) return;
    float4 f  = *(const float4*)&ef[(size_t)e*ED + sub*4];
    float4 A1 = *(const float4*)&a1e[sub*4];
    float4 A2 = *(const float4*)&a2e[sub*4];
    float4 A3 = *(const float4*)&a3e[sub*4];
    float q1 = fmaf(f.x,A1.x, fmaf(f.y,A1.y, fmaf(f.z,A1.z, f.w*A1.w)));
    float q2 = fmaf(f.x,A2.x, fmaf(f.y,A2.y, fmaf(f.z,A2.z, f.w*A2.w)));
    float q3 = fmaf(f.x,A3.x, fmaf(f.y,A3.y, fmaf(f.z,A3.z, f.w*A3.w)));
    q1 += __shfl_xor(q1,1); q1 += __shfl_xor(q1,2);
    q2 += __shfl_xor(q2,1); q2 += __shfl_xor(q2,2);
    q3 += __shfl_xor(q3,1); q3 += __shfl_xor(q3,2);
    if(sub == 0){
      uint2 A;
      A.x = (unsigned)f2b(q1) | ((unsigned)f2b(q2) << 16);
      A.y = (unsigned)src[e] | ((unsigned)f2b(q3) << 16);
      pay[e] = A;
    }
    return;
  }
  b -= NE4;
  if(b < 24){
    // ---- W swizzle (3 layers x 2048 rows) ----
    int idx = b*256 + threadIdx.x;
    if(idx >= 3*2048) return;
    int layer = idx >> 11;
    int r = idx & 2047;
    const float* W = (layer==0)?W1:((layer==1)?W2:W3);
    int lane = r & 63, tile = r >> 6;
    int kt = tile >> 3, nt = tile & 7;
    int qq = lane >> 4, cc = lane & 15;
    int kbase = kt*32 + qq*8;
    int col = nt*16 + cc;
    unsigned short tmp[8];
    #pragma unroll
    for(int j=0;j<8;j++) tmp[j] = f2b(W[(size_t)(kbase+j)*HD + col]);
    uint4 o;
    o.x = tmp[0]|((unsigned)tmp[1]<<16); o.y = tmp[2]|((unsigned)tmp[3]<<16);
    o.z = tmp[4]|((unsigned)tmp[5]<<16); o.w = tmp[6]|((unsigned)tmp[7]<<16);
    *(uint4*)&Wb[(size_t)idx*8] = o;
    return;
  }
  b -= 24;
  if(b == 0){
    // ---- per-graph node counts ----
    int g = threadIdx.x;
    if(g >= NG) return;
    int lo=0, hi=N;
    while(lo<hi){ int mid=(lo+hi)>>1; if(gid[mid] < g) lo=mid+1; else hi=mid; }
    int start = lo; lo = start; hi = N;
    while(lo<hi){ int mid=(lo+hi)>>1; if(gid[mid] < g+1) lo=mid+1; else hi=mid; }
    cnt[g] = (float)(lo - start);
    return;
  }
  b -= 1;
  // ---- hg zero: 3*NG*HD floats, 24 blocks ----
  int i = (b*256 + threadIdx.x)*4;
  if(i < 3*NG*HD) *(float4*)&hg[i] = (float4){0.f,0.f,0.f,0.f};
}

// deg[i] = sum over slices; block sum -> bsum[b]  (depends on H16 complete)
__global__ __launch_bounds__(256) void k_degsum(const unsigned short* __restrict__ H16,
                                                int Nr2, int NB,
                                                int* __restrict__ deg,
                                                int* __restrict__ bsum, int N){
  __shared__ int rs[4];
  int b = blockIdx.x;
  int i = b*256 + threadIdx.x;
  int s = 0;
  if(i < N){
    for(int k=0;k<NB;k++) s += (int)H16[(size_t)k*Nr2 + i];
    deg[i] = s;
  }
  #pragma unroll
  for(int o=32;o;o>>=1) s += __shfl_xor(s,o);
  if((threadIdx.x&63)==0) rs[threadIdx.x>>6] = s;
  __syncthreads();
  if(threadIdx.x==0) bsum[b] = rs[0]+rs[1]+rs[2]+rs[3];
}

// bprop with inline prefix of bsum; emits offs and SLICE-MAJOR offs2[k][i]
__global__ __launch_bounds__(256) void k_bprop2(const int* __restrict__ deg,
                                                const int* __restrict__ bsum,
                                                const unsigned short* __restrict__ H16, int Nr2,
                                                int* __restrict__ offs,
                                                int* __restrict__ offs2, int Nr,
                                                int N, int E, int NB){
  __shared__ int sh[256];
  __shared__ int sbase;
  int b = blockIdx.x, t = threadIdx.x;
  int s = 0;
  for(int j=t; j<b; j+=256) s += bsum[j];
  #pragma unroll
  for(int o=32;o;o>>=1) s += __shfl_xor(s,o);
  if(t < 4) sh[t] = 0;
  __syncthreads();
  if((t&63)==0) sh[t>>6] = s;
  __syncthreads();
  if(t==0) sbase = sh[0]+sh[1]+sh[2]+sh[3];
  __syncthreads();
  int i = b*256 + t;
  int v = (i<N) ? deg[i] : 0;
  sh[t] = v; __syncthreads();
  for(int o=1;o<256;o<<=1){ int u = (t>=o)?sh[t-o]:0; __syncthreads(); sh[t]+=u; __syncthreads(); }
  if(i<N){
    int base = sbase + sh[t] - v;
    offs[i] = base;
    int run = base;
    for(int k=0;k<NB;k++){
      offs2[(size_t)k*Nr + i] = run;
      run += (int)H16[(size_t)k*Nr2 + i];
    }
  }
  if(b==0 && t==0) offs[N] = E;
}

// ================= device bodies reused by merged kernels =================

// THIN scatter: slice id = e>>EPB_LOG (wave-uniform), rank is LDS-local rank.
__device__ __forceinline__ void scatter_dev(int bidx,
                           const int* __restrict__ dst, const int* __restrict__ rank,
                           const uint2* __restrict__ pay,
                           const int* __restrict__ offs2, int Nr,
                           uint2* __restrict__ rec, int E){
  int e = bidx*256 + threadIdx.x;
  if(e >= E) return;
  int d = dst[e];
  int k = e >> EPB_LOG;
  int p = offs2[(size_t)k*Nr + d] + rank[e];
  rec[p] = pay[e];
}

// MFMA GEMM tile + fused pdots. A-operand: bf16 (Ab) or f32 (Af, converted
// in-register with identical rounding).
__device__ __forceinline__ void gemm_dev(int bidx,
    const unsigned short* __restrict__ Ab,
    const float* __restrict__ Af,
    const unsigned short* __restrict__ Wb,
    unsigned short* __restrict__ Zb,
    const float* __restrict__ avec,
    float* __restrict__ ps, float* __restrict__ pd, int M)
{
  int tid = threadIdx.x;
  int w = tid >> 6, lane = tid & 63;
  int q = lane >> 4, c = lane & 15;
  int rowbase = bidx*128 + w*32;
  f32x4 acc[2][8];
  #pragma unroll
  for(int t=0;t<2;t++)
    #pragma unroll
    for(int n=0;n<8;n++) acc[t][n] = (f32x4){0.f,0.f,0.f,0.f};

  int r0 = rowbase + c;      if(r0 > M-1) r0 = M-1;
  int r1 = rowbase + 16 + c; if(r1 > M-1) r1 = M-1;
  #pragma unroll
  for(int kt=0; kt<4; kt++){
    int ko = kt*32 + q*8;
    bf16x8 a0, a1;
    if(Af){
      a0 = ld8f32_bf16(&Af[(size_t)r0*HD + ko]);
      a1 = ld8f32_bf16(&Af[(size_t)r1*HD + ko]);
    } else {
      a0 = __builtin_bit_cast(bf16x8, *(const uint4*)&Ab[(size_t)r0*HD + ko]);
      a1 = __builtin_bit_cast(bf16x8, *(const uint4*)&Ab[(size_t)r1*HD + ko]);
    }
    #pragma unroll
    for(int n=0;n<8;n++){
      bf16x8 b = __builtin_bit_cast(bf16x8, *(const uint4*)&Wb[(((size_t)(kt*8+n))*64 + lane)*8]);
      acc[0][n] = __builtin_amdgcn_mfma_f32_16x16x32_bf16(a0, b, acc[0][n], 0,0,0);
      acc[1][n] = __builtin_amdgcn_mfma_f32_16x16x32_bf16(a1, b, acc[1][n], 0,0,0);
    }
  }
  float asv[8], adv[8];
  #pragma unroll
  for(int n=0;n<8;n++){ asv[n] = avec[n*16+c]; adv[n] = avec[HD + n*16+c]; }
  #pragma unroll
  for(int t=0;t<2;t++){
    #pragma unroll
    for(int r=0;r<4;r++){
      int grow = rowbase + t*16 + 4*q + r;
      bool ok = grow < M;
      #pragma unroll
      for(int n=0;n<8;n++){
        if(ok) Zb[(size_t)grow*HD + n*16 + c] = f2b(acc[t][n][r]);
      }
      float pp = 0.f, dd = 0.f;
      #pragma unroll
      for(int n=0;n<8;n++){ pp = fmaf(acc[t][n][r], asv[n], pp); dd = fmaf(acc[t][n][r], adv[n], dd); }
      #pragma unroll
      for(int o=1;o<16;o<<=1){ pp += __shfl_xor(pp,o); dd += __shfl_xor(dd,o); }
      if(ok && c==0){ ps[grow] = pp; pd[grow] = dd; }
    }
  }
}

// readout chunk, 256-thread shape: 4 chunks (one per 64-lane group) of one graph
#define RCH 16
__device__ __forceinline__ void readout_dev(int rb,
                          const unsigned* __restrict__ hbu,
                          const float* __restrict__ att,
                          const int* __restrict__ gid,
                          float* __restrict__ hg, int N){
  int g = rb >> 2;
  int chunk = ((rb & 3) << 2) + (threadIdx.x >> 6);
  int t = threadIdx.x & 63;
  int lo=0, hi=N;
  while(lo<hi){ int mid=(lo+hi)>>1; if(gid[mid] < g) lo=mid+1; else hi=mid; }
  int start = lo; lo = start; hi = N;
  while(lo<hi){ int mid=(lo+hi)>>1; if(gid[mid] < g+1) lo=mid+1; else hi=mid; }
  int end = lo;
  int len = end - start;
  int c0 = start + (int)(((long long)len * chunk) / RCH);
  int c1 = start + (int)(((long long)len * (chunk+1)) / RCH);
  float acc0 = 0.f, acc1 = 0.f;
  for(int v=c0; v<c1; v++){
    unsigned P = hbu[(size_t)v*64 + t];
    float a = att[v];
    acc0 = fmaf(a, blo(P), acc0);
    acc1 = fmaf(a, bhi(P), acc1);
  }
  atomicAdd(&hg[g*HD + 2*t],     acc0);
  atomicAdd(&hg[g*HD + 2*t + 1], acc1);
}

// ================= merged dispatches =================
// thin-scatter ∥ gemm(layer1, f32 A-path)
__global__ __launch_bounds__(256) void k_sg1(
    const float* __restrict__ x, const unsigned short* __restrict__ Wb,
    unsigned short* __restrict__ Zb, const float* __restrict__ avec,
    float* __restrict__ ps, float* __restrict__ pd, int M, int GB,
    const int* __restrict__ dst, const int* __restrict__ rank,
    const uint2* __restrict__ pay,
    const int* __restrict__ offs2, int Nr, uint2* __restrict__ rec, int E){
  if(blockIdx.x < GB) gemm_dev(blockIdx.x, (const unsigned short*)0, x, Wb, Zb, avec, ps, pd, M);
  else scatter_dev(blockIdx.x - GB, dst, rank, pay, offs2, Nr, rec, E);
}

// readout(L) ∥ gemm(L+1)
__global__ __launch_bounds__(256) void k_rg(
    const unsigned short* __restrict__ Ab, const unsigned short* __restrict__ Wb,
    unsigned short* __restrict__ Zb, const float* __restrict__ avec,
    float* __restrict__ ps, float* __restrict__ pd, int M, int GB,
    const unsigned* __restrict__ hbu, const float* __restrict__ att,
    const int* __restrict__ gid, float* __restrict__ hg, int N){
  if(blockIdx.x < GB) gemm_dev(blockIdx.x, Ab, (const float*)0, Wb, Zb, avec, ps, pd, M);
  else readout_dev(blockIdx.x - GB, hbu, att, gid, hg, N);
}

// ---------------- fused logits + softmax + aggregate + relu + h(bf16) + att ----------------
// PROVEN 43us inner structure (R2), GRID-STRIDE (R13): 2048 long-lived blocks.
__global__ __launch_bounds__(256) void k_agg2(const uint4* __restrict__ zb4,
                                              const int* __restrict__ offs,
                                              const uint2* __restrict__ rec,
                                              const float* __restrict__ ps,
                                              const float* __restrict__ pd,
                                              int layer,
                                              unsigned* __restrict__ hbu,
                                              float* __restrict__ att,
                                              const float* __restrict__ watt,
                                              const float* __restrict__ batt, int N){
  int lane = threadIdx.x & 63;
  int q = lane >> 4, c = lane & 15;
  float4 w0v = *(const float4*)&watt[c*8];
  float4 w1v = *(const float4*)&watt[c*8+4];
  float bat = batt[0];
  int stride = gridDim.x << 2;

  for(int wid = blockIdx.x*4 + (threadIdx.x>>6); wid < N; wid += stride){
    int d0 = offs[wid], d1 = offs[wid+1];
    float pdv = pd[wid];
    float acc[8];
    #pragma unroll
    for(int i=0;i<8;i++) acc[i]=0.f;
    float ssum = 0.f;

    for(int t0=d0; t0<d1; t0+=64){
      int rem = d1 - t0; if(rem > 64) rem = 64;
      // ---- phase 1: per-lane edge weight ----
      int j = t0 + lane;
      float w = 0.f; int u = 0;
      if(j < d1){
        uint2 R = rec[j];
        u = (int)(R.y & 0xffffu);
        unsigned qb = (layer==0) ? (R.x & 0xffffu) : (layer==1 ? (R.x >> 16) : (R.y >> 16));
        float ql = __uint_as_float(qb << 16);
        float l = ps[u] + pdv + ql;
        l = (l >= 0.f) ? l : 0.2f*l;
        w = __expf(l);
      }
      float ws = w;
      #pragma unroll
      for(int o=32;o;o>>=1) ws += __shfl_xor(ws,o);
      ssum += ws;
      // ---- phase 2: 16 edges per iteration ----
      for(int jb=0; jb<rem; jb+=16){
        float w0 = bperm_f(jb+q,    w);  int u0 = bperm_i(jb+q,    u);
        float w1 = bperm_f(jb+4+q,  w);  int u1 = bperm_i(jb+4+q,  u);
        float w2 = bperm_f(jb+8+q,  w);  int u2 = bperm_i(jb+8+q,  u);
        float w3 = bperm_f(jb+12+q, w);  int u3 = bperm_i(jb+12+q, u);
        uint4 P0 = zb4[(size_t)u0*16 + c];
        uint4 P1 = zb4[(size_t)u1*16 + c];
        uint4 P2 = zb4[(size_t)u2*16 + c];
        uint4 P3 = zb4[(size_t)u3*16 + c];
        acc[0] = fmaf(w0, blo(P0.x), acc[0]); acc[1] = fmaf(w0, bhi(P0.x), acc[1]);
        acc[2] = fmaf(w0, blo(P0.y), acc[2]); acc[3] = fmaf(w0, bhi(P0.y), acc[3]);
        acc[4] = fmaf(w0, blo(P0.z), acc[4]); acc[5] = fmaf(w0, bhi(P0.z), acc[5]);
        acc[6] = fmaf(w0, blo(P0.w), acc[6]); acc[7] = fmaf(w0, bhi(P0.w), acc[7]);
        acc[0] = fmaf(w1, blo(P1.x), acc[0]); acc[1] = fmaf(w1, bhi(P1.x), acc[1]);
        acc[2] = fmaf(w1, blo(P1.y), acc[2]); acc[3] = fmaf(w1, bhi(P1.y), acc[3]);
        acc[4] = fmaf(w1, blo(P1.z), acc[4]); acc[5] = fmaf(w1, bhi(P1.z), acc[5]);
        acc[6] = fmaf(w1, blo(P1.w), acc[6]); acc[7] = fmaf(w1, bhi(P1.w), acc[7]);
        acc[0] = fmaf(w2, blo(P2.x), acc[0]); acc[1] = fmaf(w2, bhi(P2.x), acc[1]);
        acc[2] = fmaf(w2, blo(P2.y), acc[2]); acc[3] = fmaf(w2, bhi(P2.y), acc[3]);
        acc[4] = fmaf(w2, blo(P2.z), acc[4]); acc[5] = fmaf(w2, bhi(P2.z), acc[5]);
        acc[6] = fmaf(w2, blo(P2.w), acc[6]); acc[7] = fmaf(w2, bhi(P2.w), acc[7]);
        acc[0] = fmaf(w3, blo(P3.x), acc[0]); acc[1] = fmaf(w3, bhi(P3.x), acc[1]);
        acc[2] = fmaf(w3, blo(P3.y), acc[2]); acc[3] = fmaf(w3, bhi(P3.y), acc[3]);
        acc[4] = fmaf(w3, blo(P3.z), acc[4]); acc[5] = fmaf(w3, bhi(P3.z), acc[5]);
        acc[6] = fmaf(w3, blo(P3.w), acc[6]); acc[7] = fmaf(w3, bhi(P3.w), acc[7]);
      }
    }
    #pragma unroll
    for(int i=0;i<8;i++){ acc[i] += __shfl_xor(acc[i],16); acc[i] += __shfl_xor(acc[i],32); }
    float inv = (d1 > d0) ? 1.0f/ssum : 0.0f;
    #pragma unroll
    for(int i=0;i<8;i++) acc[i] = fmaxf(acc[i]*inv, 0.f);
    hbu[(size_t)wid*64 + c*4 + q] = (unsigned)f2b(acc[2*q]) | ((unsigned)f2b(acc[2*q+1])<<16);
    float t = acc[0]*w0v.x + acc[1]*w0v.y + acc[2]*w0v.z + acc[3]*w0v.w
            + acc[4]*w1v.x + acc[5]*w1v.y + acc[6]*w1v.z + acc[7]*w1v.w;
    #pragma unroll
    for(int o=1;o<16;o<<=1) t += __shfl_xor(t,o);
    t += bat;
    float lr = (t >= 0.f) ? t : 0.01f*t;
    if(lane==0) att[wid] = __expf(lr);
  }
}

// ---------------- standalone readout for layer 3 ----------------
__global__ __launch_bounds__(64) void k_readout(const unsigned* __restrict__ hbu,
                                                const float* __restrict__ att,
                                                const int* __restrict__ gid,
                                                float* __restrict__ hg, int N){
  int g = blockIdx.x / RCH;
  int chunk = blockIdx.x % RCH;
  int t = threadIdx.x;
  int lo=0, hi=N;
  while(lo<hi){ int mid=(lo+hi)>>1; if(gid[mid] < g) lo=mid+1; else hi=mid; }
  int start = lo; lo = start; hi = N;
  while(lo<hi){ int mid=(lo+hi)>>1; if(gid[mid] < g+1) lo=mid+1; else hi=mid; }
  int end = lo;
  int len = end - start;
  int c0 = start + (int)(((long long)len * chunk) / RCH);
  int c1 = start + (int)(((long long)len * (chunk+1)) / RCH);
  float acc0 = 0.f, acc1 = 0.f;
  for(int v=c0; v<c1; v++){
    unsigned P = hbu[(size_t)v*64 + t];
    float a = att[v];
    acc0 = fmaf(a, blo(P), acc0);
    acc1 = fmaf(a, bhi(P), acc1);
  }
  atomicAdd(&hg[g*HD + 2*t],     acc0);
  atomicAdd(&hg[g*HD + 2*t + 1], acc1);
}

// ---------------- final classifier + log_softmax (block per graph) ----------------
__global__ __launch_bounds__(384) void k_final(const float* __restrict__ hg,
                                               const float* __restrict__ cnt,
                                               const float* __restrict__ Wc,
                                               const float* __restrict__ bc,
                                               float* __restrict__ out){
  int g = blockIdx.x;
  int t = threadIdx.x;
  __shared__ float red[6];
  __shared__ float yv[NC];
  float invc = 1.f / fmaxf(cnt[g], 1.f);
  int part = t >> 7;
  int f = t & 127;
  float v = hg[(size_t)part*NG*HD + g*HD + f] * invc;
  for(int c=0; c<NC; c++){
    float p = v * Wc[(size_t)t*NC + c];
    #pragma unroll
    for(int o=32;o;o>>=1) p += __shfl_xor(p,o);
    if((t&63)==0) red[t>>6] = p;
    __syncthreads();
    if(t==0) yv[c] = bc[c] + red[0]+red[1]+red[2]+red[3]+red[4]+red[5];
    __syncthreads();
  }
  if(t==0){
    float mx = -INFINITY;
    #pragma unroll
    for(int c=0;c<NC;c++) mx = fmaxf(mx, yv[c]);
    float s = 0.f;
    #pragma unroll
    for(int c=0;c<NC;c++) s += __expf(yv[c] - mx);
    float ls = logf(s);
    #pragma unroll
    for(int c=0;c<NC;c++) out[g*NC + c] = yv[c] - mx - ls;
  }
}

// ---------------- host ----------------
extern "C" void kernel_launch(void* const* d_in, const int* in_sizes, int n_in,
                              void* d_out, int out_size, void* d_ws, size_t ws_size,
                              hipStream_t stream) {
  const float* x     = (const float*)d_in[0];
  const float* efeat = (const float*)d_in[1];
  const int*   src   = (const int*)d_in[2];
  const int*   dst   = (const int*)d_in[3];
  const int*   gid   = (const int*)d_in[4];
  const float* W1    = (const float*)d_in[5];
  const float* a1    = (const float*)d_in[6];
  const float* W2    = (const float*)d_in[7];
  const float* a2    = (const float*)d_in[8];
  const float* W3    = (const float*)d_in[9];
  const float* a3    = (const float*)d_in[10];
  const float* watt  = (const float*)d_in[11];
  const float* batt  = (const float*)d_in[12];
  const float* Wc    = (const float*)d_in[13];
  const float* bc    = (const float*)d_in[14];
  float* out = (float*)d_out;

  int N = in_sizes[4];
  int E = in_sizes[2];
  int Nr = (N + 63) & ~63;                    // offs2 node stride
  int NB = (E + EPB - 1) >> EPB_LOG;          // hist slices
  int NP = (N + EPB - 1) >> EPB_LOG;          // node-range passes
  int NBH = NB * NP;                          // hist blocks
  int Nr2 = NP << EPB_LOG;                    // H16 node stride

  char* p = (char*)d_ws;
  auto alloc = [&](size_t bytes)->void*{
    void* r = (void*)p;
    p += (bytes + 255) & ~(size_t)255;
    return r;
  };
  unsigned short* Hb = (unsigned short*)alloc((size_t)N*HD*2);
  unsigned short* Zb = (unsigned short*)alloc((size_t)N*HD*2);
  unsigned short* Wball = (unsigned short*)alloc((size_t)3*2048*8*2);
  float* ps      = (float*)alloc((size_t)N*4);
  float* pd      = (float*)alloc((size_t)N*4);
  float* att     = (float*)alloc((size_t)N*4);
  int*   deg     = (int*)  alloc((size_t)N*4);
  int*   offs    = (int*)  alloc((size_t)(N+1)*4);
  int*   offs2   = (int*)  alloc((size_t)NB*Nr*4);
  unsigned short* H16 = (unsigned short*)alloc((size_t)NB*Nr2*2);
  int*   rank    = (int*)  alloc((size_t)E*4);
  uint2* pay     = (uint2*)alloc((size_t)E*8);
  uint2* rec     = (uint2*)alloc((size_t)E*8);
  int*   bsum    = (int*)  alloc((size_t)1024*4);
  float* hg      = (float*)alloc((size_t)3*NG*HD*4);
  float* cnt     = (float*)alloc((size_t)NG*4);
  (void)ws_size; (void)n_in; (void)out_size;

  int nb = (N + 255) / 256;
  int NE4 = (E*4 + 255) / 256;
  int GB = (N + 127) / 128;
  int SB = (E + 255) / 256;
  int nagg = (N + 3) / 4; if(nagg > 2048) nagg = 2048;

  // CSR build with LDS histograms (merged: hist hides under streams)
  k_pre<<<NBH + NE4 + 24 + 1 + 24, 256, 0, stream>>>(dst, H16, Nr2, rank, NBH, NP,
                                                     NE4, E,
                                                     src, efeat, a1+2*HD, a2+2*HD, a3+2*HD, pay,
                                                     W1, W2, W3, Wball,
                                                     gid, cnt, hg, N);
  k_degsum<<<nb, 256, 0, stream>>>(H16, Nr2, NB, deg, bsum, N);
  k_bprop2<<<nb, 256, 0, stream>>>(deg, bsum, H16, Nr2, offs, offs2, Nr, N, E, NB);
  // thin scatter ∥ gemm layer 1 (f32 A-path)
  k_sg1<<<GB + SB, 256, 0, stream>>>(x, Wball, Zb, a1, ps, pd, N, GB,
                                     dst, rank, pay, offs2, Nr, rec, E);
  k_agg2<<<nagg, 256, 0, stream>>>((const uint4*)Zb, offs, rec, ps, pd, 0,
                                   (unsigned*)Hb, att, watt, batt, N);
  // readout L1 ∥ gemm L2
  k_rg<<<GB + NG*4, 256, 0, stream>>>(Hb, Wball + (size_t)1*2048*8, Zb, a2, ps, pd, N, GB,
                                      (const unsigned*)Hb, att, gid, hg + 0*NG*HD, N);
  k_agg2<<<nagg, 256, 0, stream>>>((const uint4*)Zb, offs, rec, ps, pd, 1,
                                   (unsigned*)Hb, att, watt, batt, N);
  // readout L2 ∥ gemm L3
  k_rg<<<GB + NG*4, 256, 0, stream>>>(Hb, Wball + (size_t)2*2048*8, Zb, a3, ps, pd, N, GB,
                                      (const unsigned*)Hb, att, gid, hg + 1*NG*HD, N);
  k_agg2<<<nagg, 256, 0, stream>>>((const uint4*)Zb, offs, rec, ps, pd, 2,
                                   (unsigned*)Hb, att, watt, batt, N);
  k_readout<<<NG*RCH, 64, 0, stream>>>((const unsigned*)Hb, att, gid,
                                       hg + 2*NG*HD, N);
  k_final<<<NG, 384, 0, stream>>>(hg, cnt, Wc, bc, out);
}